// Round 23
// baseline (597.385 us; speedup 1.0000x reference)
//
#include <hip/hip_runtime.h>
#include <hip/hip_bf16.h>
#include <stdint.h>

// ---------------- configuration ----------------
// VERIFIED R8: threefry partitionable xor-fold (y0^y1), f32 outputs
// R21: fixed-shift softmax (C=96). R22: single-exp epilogue (e<=0 weights subnormal).
// R23: k_mask caches payloads in LDS (single threefry pass).

#define N_NODES 6000
#define NPAD    6016
#define FDIM    512
#define TDIM    256
#define DDIM    64
#define NHEAD   4
#define MWORDS  94
#define CSHIFT  96.0f
#define PAYC    4096

typedef unsigned int        u32;
typedef unsigned long long  u64;
typedef unsigned short      u16;
typedef __attribute__((ext_vector_type(8))) short    bf16x8;
typedef __attribute__((ext_vector_type(8))) _Float16 f16x8;
typedef __attribute__((ext_vector_type(4))) float    f32x4;

__device__ __forceinline__ u16 f2bf(float f) {
  __hip_bfloat16 h = __float2bfloat16(f);
  return *(u16*)&h;
}

// ---------------- threefry2x32, key = (0, 42), partitionable xor-fold ----------------
__device__ __forceinline__ u32 prng_payload(u32 m, u32 j) {
  u32 flat = m * 6000u + j;
  u32 x0 = 0u, x1 = flat;
  const u32 k0 = 0u, k1 = 42u;
  const u32 k2 = 0x1BD11BDAu ^ k0 ^ k1;
  x0 += k0; x1 += k1;
#define TFR(R) { x0 += x1; x1 = (x1 << (R)) | (x1 >> (32 - (R))); x1 ^= x0; }
  TFR(13) TFR(15) TFR(26) TFR(6)
  x0 += k1; x1 += k2 + 1u;
  TFR(17) TFR(29) TFR(16) TFR(24)
  x0 += k2; x1 += k0 + 2u;
  TFR(13) TFR(15) TFR(26) TFR(6)
  x0 += k0; x1 += k1 + 3u;
  TFR(17) TFR(29) TFR(16) TFR(24)
  x0 += k1; x1 += k2 + 4u;
  TFR(13) TFR(15) TFR(26) TFR(6)
  x0 += k2; x1 += k0 + 5u;
#undef TFR
  return (x0 ^ x1) >> 9;   // 23-bit payload; uniform monotone in this
}

// ---------------- prep: bf16 casts + class extraction ----------------
__global__ void k_prep(const float* __restrict__ fs, const float* __restrict__ fcw,
                       const float* __restrict__ decw,
                       u16* __restrict__ fs_b, u16* __restrict__ fcw_b,
                       u16* __restrict__ decw_b, u32* __restrict__ cls) {
  size_t i = (size_t)blockIdx.x * 256 + threadIdx.x;
  if (i < (size_t)NPAD * FDIM) {
    size_t n = i / FDIM;
    float v = (n < N_NODES) ? fs[(size_t)n * FDIM + (i % FDIM)] : 0.f;
    fs_b[i] = f2bf(v);
  }
  if (i < (size_t)TDIM * FDIM) fcw_b[i] = f2bf(fcw[i]);
  if (i < (size_t)FDIM * TDIM) decw_b[i] = f2bf(decw[i]);
  if (i < NPAD) cls[i] = (i < N_NODES) ? (u32)fs[i * FDIM + FDIM - 1] : 0u;
}

// ---------------- h1 = emb_src@W (f16), g2 = (emb_dest@W)@W2 (split hi/lo f16) ----------------
__global__ __launch_bounds__(256) void k_hgen(const float* __restrict__ emb_src,
                                              const float* __restrict__ emb_dest,
                                              const float* __restrict__ W,
                                              const float* __restrict__ W2,
                                              u16* __restrict__ h1f16,
                                              u16* __restrict__ g2hi, u16* __restrict__ g2lo) {
  const int n = blockIdx.x;
  const int tid = threadIdx.x;
  const int h = tid >> 6, k = tid & 63;
  const size_t oidx = ((size_t)h * NPAD + n) * DDIM + k;
  __shared__ float h2s[NHEAD][DDIM];
  if (n >= N_NODES) {
    h1f16[oidx] = 0; g2hi[oidx] = 0; g2lo[oidx] = 0;
    return;
  }
  float a1 = 0.f, a2 = 0.f;
  const float* wp = W + (size_t)h * DDIM * DDIM + k;
  const float* es = emb_src + (size_t)n * DDIM;
  const float* ed = emb_dest + (size_t)n * DDIM;
  #pragma unroll 16
  for (int d = 0; d < DDIM; ++d) {
    float w = wp[(size_t)d * DDIM];
    a1 = fmaf(es[d], w, a1);
    a2 = fmaf(ed[d], w, a2);
  }
  _Float16 hh = (_Float16)a1;
  h1f16[oidx] = *(u16*)&hh;
  h2s[h][k] = a2;
  __syncthreads();
  float g = 0.f;
  const float* w2p = W2 + (size_t)h * DDIM * DDIM + k;
  #pragma unroll 16
  for (int d = 0; d < DDIM; ++d) g = fmaf(h2s[h][d], w2p[(size_t)d * DDIM], g);
  _Float16 gh = (_Float16)g;
  _Float16 gl = (_Float16)(g - (float)gh);
  g2hi[oidx] = *(u16*)&gh;
  g2lo[oidx] = *(u16*)&gl;
}

// ---------------- tf = fs @ fc_w^T + fc_b  (M=NPAD,N=256,K=512), tf bf16 + tf^T bf16 ----------------
__global__ __launch_bounds__(256) void k_gemm_tf(const u16* __restrict__ A,   // fs_b [NPAD][512]
                                                 const u16* __restrict__ B,   // fcw_b [256][512]
                                                 const float* __restrict__ fcb,
                                                 u16* __restrict__ tf,        // [NPAD][256] bf16
                                                 u16* __restrict__ tfT) {     // [256][NPAD] bf16
  const int r0 = blockIdx.x * 32;
  const int wave = threadIdx.x >> 6, lane = threadIdx.x & 63;
  const int lrow = lane & 15, lgrp = lane >> 4;
  const int n0 = wave * 64;
  f32x4 acc[2][4] = {};
  for (int ks = 0; ks < FDIM; ks += 32) {
    const int kb = ks + lgrp * 8;
    bf16x8 a[2], b[4];
    #pragma unroll
    for (int mi = 0; mi < 2; ++mi)
      a[mi] = *(const bf16x8*)(A + (size_t)(r0 + mi * 16 + lrow) * FDIM + kb);
    #pragma unroll
    for (int ni = 0; ni < 4; ++ni)
      b[ni] = *(const bf16x8*)(B + (size_t)(n0 + ni * 16 + lrow) * FDIM + kb);
    #pragma unroll
    for (int mi = 0; mi < 2; ++mi)
      #pragma unroll
      for (int ni = 0; ni < 4; ++ni)
        acc[mi][ni] = __builtin_amdgcn_mfma_f32_16x16x32_bf16(a[mi], b[ni], acc[mi][ni], 0, 0, 0);
  }
  #pragma unroll
  for (int mi = 0; mi < 2; ++mi)
    #pragma unroll
    for (int ni = 0; ni < 4; ++ni) {
      const int col = n0 + ni * 16 + lrow;
      const float bv = fcb[col];
      const int rbase = r0 + mi * 16 + lgrp * 4;
      union { u16 s[4]; uint2 v; } pk;
      #pragma unroll
      for (int q = 0; q < 4; ++q) {
        const int row = rbase + q;
        const float v = (row < N_NODES) ? (acc[mi][ni][q] + bv) : 0.f;
        const u16 hv = f2bf(v);
        tf[(size_t)row * TDIM + col] = hv;
        pk.s[q] = hv;
      }
      *(uint2*)(tfT + (size_t)col * NPAD + rbase) = pk.v;
    }
}

// ---------------- feature_hat = tf @ dec_w^T + dec_b  (M=NPAD,N=512,K=256) -> f32 ----------------
__global__ __launch_bounds__(256) void k_gemm_fh(const u16* __restrict__ A,   // tf [NPAD][256]
                                                 const u16* __restrict__ B,   // decw_b [512][256]
                                                 const float* __restrict__ decb,
                                                 float* __restrict__ out1) {  // [6000][512] f32
  const int r0 = blockIdx.x * 32;
  const int wave = threadIdx.x >> 6, lane = threadIdx.x & 63;
  const int lrow = lane & 15, lgrp = lane >> 4;
  const int n0 = wave * 128;
  f32x4 acc[2][8] = {};
  for (int ks = 0; ks < TDIM; ks += 32) {
    const int kb = ks + lgrp * 8;
    bf16x8 a[2], b[8];
    #pragma unroll
    for (int mi = 0; mi < 2; ++mi)
      a[mi] = *(const bf16x8*)(A + (size_t)(r0 + mi * 16 + lrow) * TDIM + kb);
    #pragma unroll
    for (int ni = 0; ni < 8; ++ni)
      b[ni] = *(const bf16x8*)(B + (size_t)(n0 + ni * 16 + lrow) * TDIM + kb);
    #pragma unroll
    for (int mi = 0; mi < 2; ++mi)
      #pragma unroll
      for (int ni = 0; ni < 8; ++ni)
        acc[mi][ni] = __builtin_amdgcn_mfma_f32_16x16x32_bf16(a[mi], b[ni], acc[mi][ni], 0, 0, 0);
  }
  #pragma unroll
  for (int mi = 0; mi < 2; ++mi)
    #pragma unroll
    for (int ni = 0; ni < 8; ++ni) {
      const int col = n0 + ni * 16 + lrow;
      const float bv = decb[col];
      const int rbase = r0 + mi * 16 + lgrp * 4;
      #pragma unroll
      for (int q = 0; q < 4; ++q) {
        const int row = rbase + q;
        if (row < N_NODES) out1[(size_t)row * FDIM + col] = acc[mi][ni][q] + bv;
      }
    }
}

// ---------------- fair_select mask: compaction + SINGLE threefry pass (payloads cached in LDS) ----------------
__global__ __launch_bounds__(256) void k_mask(const int* __restrict__ bias,
                                              const u32* __restrict__ cls,
                                              u64* __restrict__ maskbits) {
  const int m = blockIdx.x;
  const int tid = threadIdx.x;
  if (m >= N_NODES) {
    for (int t = tid; t < MWORDS; t += 256) maskbits[(size_t)m * MWORDS + t] = 0ull;
    return;
  }
  __shared__ u64 adjw[MWORDS], clsw[MWORDS], keptw[MWORDS];
  __shared__ u16 clist[NPAD];       // compacted majority-adjacent indices (12 KB)
  __shared__ u32 pay_c[PAYC];       // cached payloads by compact index (16 KB)
  __shared__ u32 wordoff[MWORDS];
  __shared__ u32 hist[256];
  __shared__ u64 tkey[128];
  __shared__ u64 thrK;
  __shared__ u32 bc[4];
  __shared__ int tie_n;
  __shared__ u32 c0s, c1s;
  if (tid == 0) { tie_n = 0; c0s = 0; c1s = 0; thrK = ~0ull; }
  hist[tid] = 0u;
  __syncthreads();
  const int w = tid >> 6, lane = tid & 63;
  for (int it = 0, base = 0; base < NPAD; ++it, base += 256) {
    const int j = base + tid;
    bool adj = false, c1b = false;
    if (j < N_NODES) {
      adj = bias[(size_t)m * N_NODES + j] != 0;
      c1b = cls[j] != 0u;
    }
    const u64 ab = __ballot(adj);
    const u64 cb = __ballot(c1b);
    const int wi = it * 4 + w;
    if (lane == 0 && wi < MWORDS) { adjw[wi] = ab; clsw[wi] = cb; }
  }
  __syncthreads();
  if (tid < MWORDS) {
    const u64 a = adjw[tid], c = clsw[tid];
    const u32 n1 = (u32)__popcll(a & c);
    const u32 n0 = (u32)__popcll(a & ~c);
    if (n1) atomicAdd(&c1s, n1);
    if (n0) atomicAdd(&c0s, n0);
  }
  __syncthreads();
  const u32 c0 = c0s, c1 = c1s;
  const bool nodrop = (c0 == 0u) || (c1 == 0u) || (c0 == c1);
  if (nodrop) {
    for (int t = tid; t < MWORDS; t += 256) maskbits[(size_t)m * MWORDS + t] = adjw[t];
    return;
  }
  const bool Mis1 = (c1 > c0);
  const u32 keep = (c0 < c1) ? c0 : c1;
  const int n = Mis1 ? (int)c1 : (int)c0;
  // word-level exclusive scan (wave 0) + atomic-free compaction
  if (tid < 64) {
    u32 cnt0w = 0;
    if (tid < MWORDS) {
      const u64 mw = adjw[tid] & (Mis1 ? clsw[tid] : ~clsw[tid]);
      cnt0w = (u32)__popcll(mw);
    }
    u32 incl = cnt0w;
    #pragma unroll
    for (int off = 1; off < 64; off <<= 1) {
      const u32 v = __shfl_up(incl, off, 64);
      if (tid >= off) incl += v;
    }
    wordoff[tid] = incl - cnt0w;
    const u32 tot0 = __shfl(incl, 63, 64);
    const int t2 = 64 + tid;
    u32 cnt1w = 0;
    if (t2 < MWORDS) {
      const u64 mw = adjw[t2] & (Mis1 ? clsw[t2] : ~clsw[t2]);
      cnt1w = (u32)__popcll(mw);
    }
    u32 incl2 = cnt1w;
    #pragma unroll
    for (int off = 1; off < 64; off <<= 1) {
      const u32 v = __shfl_up(incl2, off, 64);
      if (tid >= off) incl2 += v;
    }
    if (t2 < MWORDS) wordoff[t2] = tot0 + incl2 - cnt1w;
  }
  __syncthreads();
  for (int base = 0; base < NPAD; base += 256) {
    const int j = base + tid;
    if (j < N_NODES) {
      const int wi = j >> 6;
      const u64 mw = adjw[wi] & (Mis1 ? clsw[wi] : ~clsw[wi]);
      const u64 bitj = 1ull << (j & 63);
      if (mw & bitj) {
        const u32 rank = (u32)__popcll(mw & (bitj - 1ull));
        clist[wordoff[wi] + rank] = (u16)j;
      }
    }
  }
  __syncthreads();
  // threefry (ONCE) -> cache payload + histogram
  for (int i = tid; i < n; i += 256) {
    const u32 j = clist[i];
    const u32 p = prng_payload((u32)m, j);
    if (i < PAYC) pay_c[i] = p;
    atomicAdd(&hist[p >> 15], 1u);
  }
  __syncthreads();
  // wave-0 scan to find threshold bin
  if (tid < 64) {
    const u32 b0 = hist[tid * 4], b1 = hist[tid * 4 + 1];
    const u32 b2 = hist[tid * 4 + 2], b3 = hist[tid * 4 + 3];
    const u32 lt = b0 + b1 + b2 + b3;
    u32 incl = lt;
    #pragma unroll
    for (int off = 1; off < 64; off <<= 1) {
      const u32 v = __shfl_up(incl, off, 64);
      if (tid >= off) incl += v;
    }
    const u32 pre = incl - lt;
    if (pre < keep && keep <= incl) {
      u32 run = pre;
      u32 cc[4] = { b0, b1, b2, b3 };
      #pragma unroll
      for (int x = 0; x < 4; ++x) {
        if (run + cc[x] >= keep) { bc[0] = (u32)(tid * 4 + x); bc[1] = keep - run; break; }
        run += cc[x];
      }
    }
  }
  __syncthreads();
  const u32 bstar = bc[0], kin = bc[1];
  // init kept = minority-adjacent
  if (tid < MWORDS) keptw[tid] = adjw[tid] & (Mis1 ? ~clsw[tid] : clsw[tid]);
  __syncthreads();
  // marks from cached payloads (bin < bstar) + threshold-bin key collection
  for (int i = tid; i < n; i += 256) {
    const u32 j = clist[i];
    const u32 p = (i < PAYC) ? pay_c[i] : prng_payload((u32)m, j);
    const u32 b = p >> 15;
    if (b < bstar) {
      atomicOr(&keptw[j >> 6], 1ull << (j & 63));
    } else if (b == bstar) {
      const int pos = atomicAdd(&tie_n, 1);
      if (pos < 128) tkey[pos] = ((u64)p << 13) | j;
    }
  }
  __syncthreads();
  const int cnt = tie_n < 128 ? tie_n : 128;
  if (tid < cnt) {
    const u64 me = tkey[tid];
    int smaller = 0;
    for (int s2 = 0; s2 < cnt; ++s2) smaller += (tkey[s2] < me) ? 1 : 0;
    if (smaller == (int)kin - 1) thrK = me;
  }
  __syncthreads();
  const u64 tk = thrK;
  if (tid < cnt) {
    const u64 me = tkey[tid];
    if (me <= tk) {
      const u32 j = (u32)(me & 0x1FFFu);
      atomicOr(&keptw[j >> 6], 1ull << (j & 63));
    }
  }
  __syncthreads();
  for (int t = tid; t < MWORDS; t += 256) maskbits[(size_t)m * MWORDS + t] = keptw[t];
}

// ---------------- pass1: l = sum_kept exp(e - C) for e > 0 ----------------
// grid (94, 8, NHEAD); mask in LDS; single hw-exp epilogue; x2-unrolled prefetch
__global__ __launch_bounds__(256) void k_pass1(const u16* __restrict__ g2hi, const u16* __restrict__ g2lo,
                                               const u16* __restrict__ h1f16,
                                               const u64* __restrict__ maskbits,
                                               float* __restrict__ lpart) {
  const int r0 = blockIdx.x * 64;
  const int chunk = blockIdx.y;       // 0..7, 768 cols (last: 640)
  const int h = blockIdx.z;           // head
  const int c0 = chunk * 768;
  const int ntw = (chunk < 7) ? 12 : 10;
  const int wave = threadIdx.x >> 6, lane = threadIdx.x & 63;
  const int lrow = lane & 15, lgrp = lane >> 4;
  const u32 cbit = (u32)(wave * 16 + lrow);
  __shared__ float red_l[4][64];
  __shared__ u64 mk[64][12];
  {
    const int wb = chunk * 12;
    for (int i = threadIdx.x; i < 64 * 12; i += 256) {
      const int r = i / 12, wi = i % 12;
      mk[r][wi] = (wb + wi < MWORDS) ? maskbits[(size_t)(r0 + r) * MWORDS + wb + wi] : 0ull;
    }
  }
  __syncthreads();
  f16x8 ahi[4][2], alo[4][2];
  #pragma unroll
  for (int mi = 0; mi < 4; ++mi)
    #pragma unroll
    for (int ks = 0; ks < 2; ++ks) {
      const size_t off = ((size_t)h * NPAD + (r0 + mi * 16 + lrow)) * DDIM + ks * 32 + lgrp * 8;
      ahi[mi][ks] = *(const f16x8*)(g2hi + off);
      alo[mi][ks] = *(const f16x8*)(g2lo + off);
    }
  float lreg[4][4];
  #pragma unroll
  for (int mi = 0; mi < 4; ++mi)
    #pragma unroll
    for (int q = 0; q < 4; ++q) lreg[mi][q] = 0.f;
  const u16* hb = h1f16 + (size_t)h * NPAD * DDIM + lrow * DDIM + lgrp * 8;
  auto loadB = [&](f16x8* dst, int i) {
    const int ii = (i < ntw) ? i : (ntw - 1);
    const size_t off = (size_t)(c0 + (wave + 4 * ii) * 16) * DDIM;
    dst[0] = *(const f16x8*)(hb + off);
    dst[1] = *(const f16x8*)(hb + off + 32);
  };
  auto compute = [&](int i, const f16x8* b) {
    f32x4 acc[4] = {};
    #pragma unroll
    for (int ks = 0; ks < 2; ++ks)
      #pragma unroll
      for (int mi = 0; mi < 4; ++mi) {
        acc[mi] = __builtin_amdgcn_mfma_f32_16x16x32_f16(ahi[mi][ks], b[ks], acc[mi], 0, 0, 0);
        acc[mi] = __builtin_amdgcn_mfma_f32_16x16x32_f16(alo[mi][ks], b[ks], acc[mi], 0, 0, 0);
      }
    #pragma unroll
    for (int mi = 0; mi < 4; ++mi)
      #pragma unroll
      for (int q = 0; q < 4; ++q) {
        const int rowl = mi * 16 + lgrp * 4 + q;
        const bool kept = (mk[rowl][i] >> cbit) & 1ull;
        const float e = acc[mi][q];
        lreg[mi][q] += (kept && e > 0.f) ? __expf(e - CSHIFT) : 0.f;
      }
  };
  f16x8 bA[2], bB[2];
  loadB(bA, 0); loadB(bB, 1);
  for (int i = 0; i < ntw; i += 2) {
    f16x8 nA[2], nB[2];
    loadB(nA, i + 2);
    loadB(nB, i + 3);
    compute(i, bA);
    compute(i + 1, bB);
    bA[0] = nA[0]; bA[1] = nA[1];
    bB[0] = nB[0]; bB[1] = nB[1];
  }
  #pragma unroll
  for (int mi = 0; mi < 4; ++mi)
    #pragma unroll
    for (int q = 0; q < 4; ++q) {
      float l0 = lreg[mi][q];
      #pragma unroll
      for (int s = 1; s < 16; s <<= 1) l0 += __shfl_xor(l0, s, 64);
      lreg[mi][q] = l0;
    }
  if (lrow == 0) {
    #pragma unroll
    for (int mi = 0; mi < 4; ++mi)
      #pragma unroll
      for (int q = 0; q < 4; ++q) {
        const int rl = mi * 16 + lgrp * 4 + q;
        red_l[wave][rl] = lreg[mi][q];
      }
  }
  __syncthreads();
  if (threadIdx.x < 64) {
    const int rl = threadIdx.x;
    const float l0 = red_l[0][rl] + red_l[1][rl] + red_l[2][rl] + red_l[3][rl];
    const size_t o = ((size_t)chunk * NHEAD + h) * NPAD + r0 + rl;
    lpart[o] = l0;
  }
}

// ---------------- merge partial l over the 8 column chunks ----------------
__global__ void k_merge(const float* __restrict__ lpart, float* __restrict__ lfin) {
  const int i = blockIdx.x * 256 + threadIdx.x;
  if (i >= NHEAD * NPAD) return;
  float l0 = 0.f;
  #pragma unroll
  for (int c = 0; c < 8; ++c) l0 += lpart[(size_t)c * (NHEAD * NPAD) + i];
  lfin[i] = l0;
}

// ---------------- pass2: A[m][n] = sum_h attn_h[m][n]  (bf16), R18 shape + single-exp epilogue ----------------
__global__ __launch_bounds__(256) void k_pass2(const u16* __restrict__ g2hi, const u16* __restrict__ g2lo,
                                               const u16* __restrict__ h1f16,
                                               const u64* __restrict__ maskbits,
                                               const float* __restrict__ lfin,
                                               u16* __restrict__ Amat) {
  const int r0 = blockIdx.x * 32;
  const int chunk = blockIdx.y;          // 0..23, 256 cols each (last: 128)
  const int c0 = chunk * 256;
  const int nt = (chunk < 23) ? 16 : 8;
  const int wave = threadIdx.x >> 6, lane = threadIdx.x & 63;
  const int lrow = lane & 15, lgrp = lane >> 4;
  const u32 cbit = (u32)(wave * 16 + lrow);
  __shared__ float sv[NHEAD][32], suS[32];
  __shared__ u64 mk[32][4];
  if (threadIdx.x < NHEAD * 32) {
    const int h = threadIdx.x >> 5, rl = threadIdx.x & 31;
    const float lv = lfin[(size_t)h * NPAD + r0 + rl];
    sv[h][rl] = (lv > 0.f) ? (1.f / lv) : 0.f;
  }
  if (threadIdx.x >= 128 && threadIdx.x < 160) {
    const int rl = threadIdx.x - 128;
    float s = 0.f;
    #pragma unroll
    for (int h = 0; h < NHEAD; ++h) {
      const float lv = lfin[(size_t)h * NPAD + r0 + rl];
      s += (lv > 0.f) ? 0.f : (1.f / 6000.f);  // empty row: uniform fallback
    }
    suS[rl] = s;
  }
  {
    const int wb = chunk * 4;
    for (int i = threadIdx.x; i < 32 * 4; i += 256) {
      const int r = i >> 2, wi = i & 3;
      mk[r][wi] = (wb + wi < MWORDS) ? maskbits[(size_t)(r0 + r) * MWORDS + wb + wi] : 0ull;
    }
  }
  __syncthreads();
  const int ntw = nt >> 2;
  f32x4 wsum[4][2] = {};
  #pragma unroll
  for (int h = 0; h < NHEAD; ++h) {
    f16x8 ahi[2][2], alo[2][2];
    #pragma unroll
    for (int mi = 0; mi < 2; ++mi)
      #pragma unroll
      for (int ks = 0; ks < 2; ++ks) {
        const size_t off = ((size_t)h * NPAD + (r0 + mi * 16 + lrow)) * DDIM + ks * 32 + lgrp * 8;
        ahi[mi][ks] = *(const f16x8*)(g2hi + off);
        alo[mi][ks] = *(const f16x8*)(g2lo + off);
      }
    const u16* hb = h1f16 + (size_t)h * NPAD * DDIM + lrow * DDIM + lgrp * 8;
    auto loadB = [&](f16x8* dst, int i) {
      const int ii = (i < ntw) ? i : (ntw - 1);
      const size_t off = (size_t)(c0 + (wave + 4 * ii) * 16) * DDIM;
      dst[0] = *(const f16x8*)(hb + off);
      dst[1] = *(const f16x8*)(hb + off + 32);
    };
    auto compute = [&](int i, const f16x8* b) {
      if (i >= ntw) return;
      f32x4 acc[2] = {};
      #pragma unroll
      for (int ks = 0; ks < 2; ++ks)
        #pragma unroll
        for (int mi = 0; mi < 2; ++mi) {
          acc[mi] = __builtin_amdgcn_mfma_f32_16x16x32_f16(ahi[mi][ks], b[ks], acc[mi], 0, 0, 0);
          acc[mi] = __builtin_amdgcn_mfma_f32_16x16x32_f16(alo[mi][ks], b[ks], acc[mi], 0, 0, 0);
        }
      #pragma unroll
      for (int mi = 0; mi < 2; ++mi)
        #pragma unroll
        for (int q = 0; q < 4; ++q) {
          const int rl = mi * 16 + lgrp * 4 + q;
          const bool kept = (mk[rl][i] >> cbit) & 1ull;
          const float v = acc[mi][q];
          wsum[i][mi][q] += (kept && v > 0.f) ? (__expf(v - CSHIFT) * sv[h][rl]) : 0.f;
        }
    };
    f16x8 b0[2], b1[2], b2[2], b3[2];
    loadB(b0, 0); loadB(b1, 1); loadB(b2, 2); loadB(b3, 3);
    compute(0, b0);
    compute(1, b1);
    compute(2, b2);
    compute(3, b3);
  }
  // write phase: add uniform fallback once, store bf16
  #pragma unroll
  for (int ti = 0; ti < 4; ++ti) {
    if (ti < ntw) {
      const int col = c0 + (wave + 4 * ti) * 16 + lrow;
      const float suAdd = (col < N_NODES) ? 1.f : 0.f;
      #pragma unroll
      for (int mi = 0; mi < 2; ++mi)
        #pragma unroll
        for (int q = 0; q < 4; ++q) {
          const int rl = mi * 16 + lgrp * 4 + q;
          const int row = r0 + rl;
          const float wv = wsum[ti][mi][q] + suAdd * suS[rl];
          Amat[(size_t)row * NPAD + col] = f2bf(wv);
        }
    }
  }
}

// ---------------- out0 = (A @ tf) / 4   (M=NPAD, N=256, K=NPAD) -> f32 ----------------
__global__ __launch_bounds__(256) void k_gemm_pv(const u16* __restrict__ Amat,
                                                 const u16* __restrict__ tfT,   // [256][NPAD]
                                                 float* __restrict__ out0) {
  const int r0 = blockIdx.x * 32;
  const int wave = threadIdx.x >> 6, lane = threadIdx.x & 63;
  const int lrow = lane & 15, lgrp = lane >> 4;
  const int n0 = wave * 64;
  f32x4 acc[2][4] = {};
  for (int ks = 0; ks < NPAD; ks += 32) {
    const int kb = ks + lgrp * 8;
    bf16x8 a[2], b[4];
    #pragma unroll
    for (int mi = 0; mi < 2; ++mi)
      a[mi] = *(const bf16x8*)(Amat + (size_t)(r0 + mi * 16 + lrow) * NPAD + kb);
    #pragma unroll
    for (int ni = 0; ni < 4; ++ni)
      b[ni] = *(const bf16x8*)(tfT + (size_t)(n0 + ni * 16 + lrow) * NPAD + kb);
    #pragma unroll
    for (int mi = 0; mi < 2; ++mi)
      #pragma unroll
      for (int ni = 0; ni < 4; ++ni)
        acc[mi][ni] = __builtin_amdgcn_mfma_f32_16x16x32_bf16(a[mi], b[ni], acc[mi][ni], 0, 0, 0);
  }
  #pragma unroll
  for (int mi = 0; mi < 2; ++mi)
    #pragma unroll
    for (int ni = 0; ni < 4; ++ni) {
      const int col = n0 + ni * 16 + lrow;
      const int rbase = r0 + mi * 16 + lgrp * 4;
      #pragma unroll
      for (int q = 0; q < 4; ++q) {
        const int row = rbase + q;
        if (row < N_NODES) out0[(size_t)row * TDIM + col] = acc[mi][ni][q] * 0.25f;
      }
    }
}

// ---------------- launcher ----------------
extern "C" void kernel_launch(void* const* d_in, const int* in_sizes, int n_in,
                              void* d_out, int out_size, void* d_ws, size_t ws_size,
                              hipStream_t stream) {
  (void)in_sizes; (void)n_in; (void)out_size; (void)ws_size;
  const int*   bias  = (const int*)  d_in[0];
  const float* emb_d = (const float*)d_in[1];
  const float* emb_s = (const float*)d_in[2];
  const float* fs    = (const float*)d_in[3];
  const float* W     = (const float*)d_in[4];
  const float* W2    = (const float*)d_in[5];
  const float* fcw   = (const float*)d_in[6];
  const float* fcb   = (const float*)d_in[7];
  const float* decw  = (const float*)d_in[8];
  const float* decb  = (const float*)d_in[9];
  float* out0 = (float*)d_out;
  float* out1 = out0 + (size_t)N_NODES * TDIM;   // f32 outputs, concatenated

  char* base = (char*)d_ws;
  size_t off = 0;
  auto alloc = [&](size_t bytes) -> void* {
    off = (off + 255) & ~(size_t)255;
    void* p = base + off;
    off += bytes;
    return p;
  };
  u16*   Amat   = (u16*)  alloc((size_t)NPAD * NPAD * 2);          // 72.4 MB
  u16*   tf_b   = (u16*)  alloc((size_t)NPAD * TDIM * 2);
  u16*   tfT_b  = (u16*)  alloc((size_t)TDIM * NPAD * 2);
  u16*   fs_b   = (u16*)  alloc((size_t)NPAD * FDIM * 2);
  u16*   fcw_b  = (u16*)  alloc((size_t)TDIM * FDIM * 2);
  u16*   decw_b = (u16*)  alloc((size_t)FDIM * TDIM * 2);
  u16*   h1f16  = (u16*)  alloc((size_t)NHEAD * NPAD * DDIM * 2);
  u16*   g2hi   = (u16*)  alloc((size_t)NHEAD * NPAD * DDIM * 2);
  u16*   g2lo   = (u16*)  alloc((size_t)NHEAD * NPAD * DDIM * 2);
  u64*   maskb  = (u64*)  alloc((size_t)NPAD * MWORDS * 8);
  float* lpart  = (float*)alloc((size_t)8 * NHEAD * NPAD * 4);
  float* lfin   = (float*)alloc((size_t)NHEAD * NPAD * 4);
  u32*   cls    = (u32*)  alloc((size_t)NPAD * 4);

  hipLaunchKernelGGL(k_prep,    dim3((NPAD * FDIM) / 256), dim3(256), 0, stream,
                     fs, fcw, decw, fs_b, fcw_b, decw_b, cls);
  hipLaunchKernelGGL(k_hgen,    dim3(NPAD),                dim3(256), 0, stream,
                     emb_s, emb_d, W, W2, h1f16, g2hi, g2lo);
  hipLaunchKernelGGL(k_gemm_tf, dim3(NPAD / 32),           dim3(256), 0, stream,
                     fs_b, fcw_b, fcb, tf_b, tfT_b);
  hipLaunchKernelGGL(k_gemm_fh, dim3(NPAD / 32),           dim3(256), 0, stream,
                     tf_b, decw_b, decb, out1);
  hipLaunchKernelGGL(k_mask,    dim3(NPAD),                dim3(256), 0, stream,
                     bias, cls, maskb);
  hipLaunchKernelGGL(k_pass1,   dim3(NPAD / 64, 8, NHEAD), dim3(256), 0, stream,
                     g2hi, g2lo, h1f16, maskb, lpart);
  hipLaunchKernelGGL(k_merge,   dim3((NHEAD * NPAD) / 256),dim3(256), 0, stream,
                     lpart, lfin);
  hipLaunchKernelGGL(k_pass2,   dim3(NPAD / 32, 24),       dim3(256), 0, stream,
                     g2hi, g2lo, h1f16, maskb, lfin, Amat);
  hipLaunchKernelGGL(k_gemm_pv, dim3(NPAD / 32),           dim3(256), 0, stream,
                     Amat, tfT_b, out0);
}

// Round 24
// 540.729 us; speedup vs baseline: 1.1048x; 1.1048x over previous
//
#include <hip/hip_runtime.h>
#include <hip/hip_bf16.h>
#include <stdint.h>

// ---------------- configuration ----------------
// VERIFIED R8: threefry partitionable xor-fold (y0^y1), f32 outputs
// R21: fixed-shift softmax (C=96). R22: single-exp epilogue (e<=0 weights subnormal).
// R24: k_mask caches payloads in REGISTERS (single threefry pass, no LDS growth).

#define N_NODES 6000
#define NPAD    6016
#define FDIM    512
#define TDIM    256
#define DDIM    64
#define NHEAD   4
#define MWORDS  94
#define CSHIFT  96.0f
#define PITER   16          // 16*256 = 4096 register-cached elements; fallback recompute beyond

typedef unsigned int        u32;
typedef unsigned long long  u64;
typedef unsigned short      u16;
typedef __attribute__((ext_vector_type(8))) short    bf16x8;
typedef __attribute__((ext_vector_type(8))) _Float16 f16x8;
typedef __attribute__((ext_vector_type(4))) float    f32x4;

__device__ __forceinline__ u16 f2bf(float f) {
  __hip_bfloat16 h = __float2bfloat16(f);
  return *(u16*)&h;
}

// ---------------- threefry2x32, key = (0, 42), partitionable xor-fold ----------------
__device__ __forceinline__ u32 prng_payload(u32 m, u32 j) {
  u32 flat = m * 6000u + j;
  u32 x0 = 0u, x1 = flat;
  const u32 k0 = 0u, k1 = 42u;
  const u32 k2 = 0x1BD11BDAu ^ k0 ^ k1;
  x0 += k0; x1 += k1;
#define TFR(R) { x0 += x1; x1 = (x1 << (R)) | (x1 >> (32 - (R))); x1 ^= x0; }
  TFR(13) TFR(15) TFR(26) TFR(6)
  x0 += k1; x1 += k2 + 1u;
  TFR(17) TFR(29) TFR(16) TFR(24)
  x0 += k2; x1 += k0 + 2u;
  TFR(13) TFR(15) TFR(26) TFR(6)
  x0 += k0; x1 += k1 + 3u;
  TFR(17) TFR(29) TFR(16) TFR(24)
  x0 += k1; x1 += k2 + 4u;
  TFR(13) TFR(15) TFR(26) TFR(6)
  x0 += k2; x1 += k0 + 5u;
#undef TFR
  return (x0 ^ x1) >> 9;   // 23-bit payload; uniform monotone in this
}

// ---------------- prep: bf16 casts + class extraction ----------------
__global__ void k_prep(const float* __restrict__ fs, const float* __restrict__ fcw,
                       const float* __restrict__ decw,
                       u16* __restrict__ fs_b, u16* __restrict__ fcw_b,
                       u16* __restrict__ decw_b, u32* __restrict__ cls) {
  size_t i = (size_t)blockIdx.x * 256 + threadIdx.x;
  if (i < (size_t)NPAD * FDIM) {
    size_t n = i / FDIM;
    float v = (n < N_NODES) ? fs[(size_t)n * FDIM + (i % FDIM)] : 0.f;
    fs_b[i] = f2bf(v);
  }
  if (i < (size_t)TDIM * FDIM) fcw_b[i] = f2bf(fcw[i]);
  if (i < (size_t)FDIM * TDIM) decw_b[i] = f2bf(decw[i]);
  if (i < NPAD) cls[i] = (i < N_NODES) ? (u32)fs[i * FDIM + FDIM - 1] : 0u;
}

// ---------------- h1 = emb_src@W (f16), g2 = (emb_dest@W)@W2 (split hi/lo f16) ----------------
__global__ __launch_bounds__(256) void k_hgen(const float* __restrict__ emb_src,
                                              const float* __restrict__ emb_dest,
                                              const float* __restrict__ W,
                                              const float* __restrict__ W2,
                                              u16* __restrict__ h1f16,
                                              u16* __restrict__ g2hi, u16* __restrict__ g2lo) {
  const int n = blockIdx.x;
  const int tid = threadIdx.x;
  const int h = tid >> 6, k = tid & 63;
  const size_t oidx = ((size_t)h * NPAD + n) * DDIM + k;
  __shared__ float h2s[NHEAD][DDIM];
  if (n >= N_NODES) {
    h1f16[oidx] = 0; g2hi[oidx] = 0; g2lo[oidx] = 0;
    return;
  }
  float a1 = 0.f, a2 = 0.f;
  const float* wp = W + (size_t)h * DDIM * DDIM + k;
  const float* es = emb_src + (size_t)n * DDIM;
  const float* ed = emb_dest + (size_t)n * DDIM;
  #pragma unroll 16
  for (int d = 0; d < DDIM; ++d) {
    float w = wp[(size_t)d * DDIM];
    a1 = fmaf(es[d], w, a1);
    a2 = fmaf(ed[d], w, a2);
  }
  _Float16 hh = (_Float16)a1;
  h1f16[oidx] = *(u16*)&hh;
  h2s[h][k] = a2;
  __syncthreads();
  float g = 0.f;
  const float* w2p = W2 + (size_t)h * DDIM * DDIM + k;
  #pragma unroll 16
  for (int d = 0; d < DDIM; ++d) g = fmaf(h2s[h][d], w2p[(size_t)d * DDIM], g);
  _Float16 gh = (_Float16)g;
  _Float16 gl = (_Float16)(g - (float)gh);
  g2hi[oidx] = *(u16*)&gh;
  g2lo[oidx] = *(u16*)&gl;
}

// ---------------- tf = fs @ fc_w^T + fc_b  (M=NPAD,N=256,K=512), tf bf16 + tf^T bf16 ----------------
__global__ __launch_bounds__(256) void k_gemm_tf(const u16* __restrict__ A,   // fs_b [NPAD][512]
                                                 const u16* __restrict__ B,   // fcw_b [256][512]
                                                 const float* __restrict__ fcb,
                                                 u16* __restrict__ tf,        // [NPAD][256] bf16
                                                 u16* __restrict__ tfT) {     // [256][NPAD] bf16
  const int r0 = blockIdx.x * 32;
  const int wave = threadIdx.x >> 6, lane = threadIdx.x & 63;
  const int lrow = lane & 15, lgrp = lane >> 4;
  const int n0 = wave * 64;
  f32x4 acc[2][4] = {};
  for (int ks = 0; ks < FDIM; ks += 32) {
    const int kb = ks + lgrp * 8;
    bf16x8 a[2], b[4];
    #pragma unroll
    for (int mi = 0; mi < 2; ++mi)
      a[mi] = *(const bf16x8*)(A + (size_t)(r0 + mi * 16 + lrow) * FDIM + kb);
    #pragma unroll
    for (int ni = 0; ni < 4; ++ni)
      b[ni] = *(const bf16x8*)(B + (size_t)(n0 + ni * 16 + lrow) * FDIM + kb);
    #pragma unroll
    for (int mi = 0; mi < 2; ++mi)
      #pragma unroll
      for (int ni = 0; ni < 4; ++ni)
        acc[mi][ni] = __builtin_amdgcn_mfma_f32_16x16x32_bf16(a[mi], b[ni], acc[mi][ni], 0, 0, 0);
  }
  #pragma unroll
  for (int mi = 0; mi < 2; ++mi)
    #pragma unroll
    for (int ni = 0; ni < 4; ++ni) {
      const int col = n0 + ni * 16 + lrow;
      const float bv = fcb[col];
      const int rbase = r0 + mi * 16 + lgrp * 4;
      union { u16 s[4]; uint2 v; } pk;
      #pragma unroll
      for (int q = 0; q < 4; ++q) {
        const int row = rbase + q;
        const float v = (row < N_NODES) ? (acc[mi][ni][q] + bv) : 0.f;
        const u16 hv = f2bf(v);
        tf[(size_t)row * TDIM + col] = hv;
        pk.s[q] = hv;
      }
      *(uint2*)(tfT + (size_t)col * NPAD + rbase) = pk.v;
    }
}

// ---------------- feature_hat = tf @ dec_w^T + dec_b  (M=NPAD,N=512,K=256) -> f32 ----------------
__global__ __launch_bounds__(256) void k_gemm_fh(const u16* __restrict__ A,   // tf [NPAD][256]
                                                 const u16* __restrict__ B,   // decw_b [512][256]
                                                 const float* __restrict__ decb,
                                                 float* __restrict__ out1) {  // [6000][512] f32
  const int r0 = blockIdx.x * 32;
  const int wave = threadIdx.x >> 6, lane = threadIdx.x & 63;
  const int lrow = lane & 15, lgrp = lane >> 4;
  const int n0 = wave * 128;
  f32x4 acc[2][8] = {};
  for (int ks = 0; ks < TDIM; ks += 32) {
    const int kb = ks + lgrp * 8;
    bf16x8 a[2], b[8];
    #pragma unroll
    for (int mi = 0; mi < 2; ++mi)
      a[mi] = *(const bf16x8*)(A + (size_t)(r0 + mi * 16 + lrow) * TDIM + kb);
    #pragma unroll
    for (int ni = 0; ni < 8; ++ni)
      b[ni] = *(const bf16x8*)(B + (size_t)(n0 + ni * 16 + lrow) * TDIM + kb);
    #pragma unroll
    for (int mi = 0; mi < 2; ++mi)
      #pragma unroll
      for (int ni = 0; ni < 8; ++ni)
        acc[mi][ni] = __builtin_amdgcn_mfma_f32_16x16x32_bf16(a[mi], b[ni], acc[mi][ni], 0, 0, 0);
  }
  #pragma unroll
  for (int mi = 0; mi < 2; ++mi)
    #pragma unroll
    for (int ni = 0; ni < 8; ++ni) {
      const int col = n0 + ni * 16 + lrow;
      const float bv = decb[col];
      const int rbase = r0 + mi * 16 + lgrp * 4;
      #pragma unroll
      for (int q = 0; q < 4; ++q) {
        const int row = rbase + q;
        if (row < N_NODES) out1[(size_t)row * FDIM + col] = acc[mi][ni][q] + bv;
      }
    }
}

// ---------------- fair_select mask: compaction + single threefry (payloads in REGISTERS) ----------------
__global__ __launch_bounds__(256) void k_mask(const int* __restrict__ bias,
                                              const u32* __restrict__ cls,
                                              u64* __restrict__ maskbits) {
  const int m = blockIdx.x;
  const int tid = threadIdx.x;
  if (m >= N_NODES) {
    for (int t = tid; t < MWORDS; t += 256) maskbits[(size_t)m * MWORDS + t] = 0ull;
    return;
  }
  __shared__ u64 adjw[MWORDS], clsw[MWORDS], keptw[MWORDS];
  __shared__ u16 clist[NPAD];       // compacted majority-adjacent indices (12 KB)
  __shared__ u32 wordoff[MWORDS];
  __shared__ u32 hist[256];
  __shared__ u64 tkey[128];
  __shared__ u64 thrK;
  __shared__ u32 bc[4];
  __shared__ int tie_n;
  __shared__ u32 c0s, c1s;
  if (tid == 0) { tie_n = 0; c0s = 0; c1s = 0; thrK = ~0ull; }
  hist[tid] = 0u;
  __syncthreads();
  const int w = tid >> 6, lane = tid & 63;
  for (int it = 0, base = 0; base < NPAD; ++it, base += 256) {
    const int j = base + tid;
    bool adj = false, c1b = false;
    if (j < N_NODES) {
      adj = bias[(size_t)m * N_NODES + j] != 0;
      c1b = cls[j] != 0u;
    }
    const u64 ab = __ballot(adj);
    const u64 cb = __ballot(c1b);
    const int wi = it * 4 + w;
    if (lane == 0 && wi < MWORDS) { adjw[wi] = ab; clsw[wi] = cb; }
  }
  __syncthreads();
  if (tid < MWORDS) {
    const u64 a = adjw[tid], c = clsw[tid];
    const u32 n1 = (u32)__popcll(a & c);
    const u32 n0 = (u32)__popcll(a & ~c);
    if (n1) atomicAdd(&c1s, n1);
    if (n0) atomicAdd(&c0s, n0);
  }
  __syncthreads();
  const u32 c0 = c0s, c1 = c1s;
  const bool nodrop = (c0 == 0u) || (c1 == 0u) || (c0 == c1);
  if (nodrop) {
    for (int t = tid; t < MWORDS; t += 256) maskbits[(size_t)m * MWORDS + t] = adjw[t];
    return;
  }
  const bool Mis1 = (c1 > c0);
  const u32 keep = (c0 < c1) ? c0 : c1;
  const int n = Mis1 ? (int)c1 : (int)c0;
  // word-level exclusive scan (wave 0) + atomic-free compaction
  if (tid < 64) {
    u32 cnt0w = 0;
    if (tid < MWORDS) {
      const u64 mw = adjw[tid] & (Mis1 ? clsw[tid] : ~clsw[tid]);
      cnt0w = (u32)__popcll(mw);
    }
    u32 incl = cnt0w;
    #pragma unroll
    for (int off = 1; off < 64; off <<= 1) {
      const u32 v = __shfl_up(incl, off, 64);
      if (tid >= off) incl += v;
    }
    wordoff[tid] = incl - cnt0w;
    const u32 tot0 = __shfl(incl, 63, 64);
    const int t2 = 64 + tid;
    u32 cnt1w = 0;
    if (t2 < MWORDS) {
      const u64 mw = adjw[t2] & (Mis1 ? clsw[t2] : ~clsw[t2]);
      cnt1w = (u32)__popcll(mw);
    }
    u32 incl2 = cnt1w;
    #pragma unroll
    for (int off = 1; off < 64; off <<= 1) {
      const u32 v = __shfl_up(incl2, off, 64);
      if (tid >= off) incl2 += v;
    }
    if (t2 < MWORDS) wordoff[t2] = tot0 + incl2 - cnt1w;
  }
  __syncthreads();
  for (int base = 0; base < NPAD; base += 256) {
    const int j = base + tid;
    if (j < N_NODES) {
      const int wi = j >> 6;
      const u64 mw = adjw[wi] & (Mis1 ? clsw[wi] : ~clsw[wi]);
      const u64 bitj = 1ull << (j & 63);
      if (mw & bitj) {
        const u32 rank = (u32)__popcll(mw & (bitj - 1ull));
        clist[wordoff[wi] + rank] = (u16)j;
      }
    }
  }
  __syncthreads();
  // threefry (ONCE) -> register-cached payload + histogram
  u32 pay_r[PITER];
  #pragma unroll
  for (int it = 0; it < PITER; ++it) {
    const int i = it * 256 + tid;
    if (i < n) {
      const u32 j = clist[i];
      const u32 p = prng_payload((u32)m, j);
      pay_r[it] = p;
      atomicAdd(&hist[p >> 15], 1u);
    }
  }
  for (int i = PITER * 256 + tid; i < n; i += 256) {   // defensive fallback (n > 4096)
    const u32 p = prng_payload((u32)m, clist[i]);
    atomicAdd(&hist[p >> 15], 1u);
  }
  __syncthreads();
  // wave-0 scan to find threshold bin
  if (tid < 64) {
    const u32 b0 = hist[tid * 4], b1 = hist[tid * 4 + 1];
    const u32 b2 = hist[tid * 4 + 2], b3 = hist[tid * 4 + 3];
    const u32 lt = b0 + b1 + b2 + b3;
    u32 incl = lt;
    #pragma unroll
    for (int off = 1; off < 64; off <<= 1) {
      const u32 v = __shfl_up(incl, off, 64);
      if (tid >= off) incl += v;
    }
    const u32 pre = incl - lt;
    if (pre < keep && keep <= incl) {
      u32 run = pre;
      u32 cc[4] = { b0, b1, b2, b3 };
      #pragma unroll
      for (int x = 0; x < 4; ++x) {
        if (run + cc[x] >= keep) { bc[0] = (u32)(tid * 4 + x); bc[1] = keep - run; break; }
        run += cc[x];
      }
    }
  }
  __syncthreads();
  const u32 bstar = bc[0], kin = bc[1];
  // init kept = minority-adjacent
  if (tid < MWORDS) keptw[tid] = adjw[tid] & (Mis1 ? ~clsw[tid] : clsw[tid]);
  __syncthreads();
  // marks from register payloads (bin < bstar) + threshold-bin key collection
  #pragma unroll
  for (int it = 0; it < PITER; ++it) {
    const int i = it * 256 + tid;
    if (i < n) {
      const u32 j = clist[i];
      const u32 p = pay_r[it];
      const u32 b = p >> 15;
      if (b < bstar) {
        atomicOr(&keptw[j >> 6], 1ull << (j & 63));
      } else if (b == bstar) {
        const int pos = atomicAdd(&tie_n, 1);
        if (pos < 128) tkey[pos] = ((u64)p << 13) | j;
      }
    }
  }
  for (int i = PITER * 256 + tid; i < n; i += 256) {   // defensive fallback
    const u32 j = clist[i];
    const u32 p = prng_payload((u32)m, j);
    const u32 b = p >> 15;
    if (b < bstar) {
      atomicOr(&keptw[j >> 6], 1ull << (j & 63));
    } else if (b == bstar) {
      const int pos = atomicAdd(&tie_n, 1);
      if (pos < 128) tkey[pos] = ((u64)p << 13) | j;
    }
  }
  __syncthreads();
  const int cnt = tie_n < 128 ? tie_n : 128;
  if (tid < cnt) {
    const u64 me = tkey[tid];
    int smaller = 0;
    for (int s2 = 0; s2 < cnt; ++s2) smaller += (tkey[s2] < me) ? 1 : 0;
    if (smaller == (int)kin - 1) thrK = me;
  }
  __syncthreads();
  const u64 tk = thrK;
  if (tid < cnt) {
    const u64 me = tkey[tid];
    if (me <= tk) {
      const u32 j = (u32)(me & 0x1FFFu);
      atomicOr(&keptw[j >> 6], 1ull << (j & 63));
    }
  }
  __syncthreads();
  for (int t = tid; t < MWORDS; t += 256) maskbits[(size_t)m * MWORDS + t] = keptw[t];
}

// ---------------- pass1: l = sum_kept exp(e - C) for e > 0 ----------------
// grid (94, 8, NHEAD); mask in LDS; single hw-exp epilogue; x2-unrolled prefetch
__global__ __launch_bounds__(256) void k_pass1(const u16* __restrict__ g2hi, const u16* __restrict__ g2lo,
                                               const u16* __restrict__ h1f16,
                                               const u64* __restrict__ maskbits,
                                               float* __restrict__ lpart) {
  const int r0 = blockIdx.x * 64;
  const int chunk = blockIdx.y;       // 0..7, 768 cols (last: 640)
  const int h = blockIdx.z;           // head
  const int c0 = chunk * 768;
  const int ntw = (chunk < 7) ? 12 : 10;
  const int wave = threadIdx.x >> 6, lane = threadIdx.x & 63;
  const int lrow = lane & 15, lgrp = lane >> 4;
  const u32 cbit = (u32)(wave * 16 + lrow);
  __shared__ float red_l[4][64];
  __shared__ u64 mk[64][12];
  {
    const int wb = chunk * 12;
    for (int i = threadIdx.x; i < 64 * 12; i += 256) {
      const int r = i / 12, wi = i % 12;
      mk[r][wi] = (wb + wi < MWORDS) ? maskbits[(size_t)(r0 + r) * MWORDS + wb + wi] : 0ull;
    }
  }
  __syncthreads();
  f16x8 ahi[4][2], alo[4][2];
  #pragma unroll
  for (int mi = 0; mi < 4; ++mi)
    #pragma unroll
    for (int ks = 0; ks < 2; ++ks) {
      const size_t off = ((size_t)h * NPAD + (r0 + mi * 16 + lrow)) * DDIM + ks * 32 + lgrp * 8;
      ahi[mi][ks] = *(const f16x8*)(g2hi + off);
      alo[mi][ks] = *(const f16x8*)(g2lo + off);
    }
  float lreg[4][4];
  #pragma unroll
  for (int mi = 0; mi < 4; ++mi)
    #pragma unroll
    for (int q = 0; q < 4; ++q) lreg[mi][q] = 0.f;
  const u16* hb = h1f16 + (size_t)h * NPAD * DDIM + lrow * DDIM + lgrp * 8;
  auto loadB = [&](f16x8* dst, int i) {
    const int ii = (i < ntw) ? i : (ntw - 1);
    const size_t off = (size_t)(c0 + (wave + 4 * ii) * 16) * DDIM;
    dst[0] = *(const f16x8*)(hb + off);
    dst[1] = *(const f16x8*)(hb + off + 32);
  };
  auto compute = [&](int i, const f16x8* b) {
    f32x4 acc[4] = {};
    #pragma unroll
    for (int ks = 0; ks < 2; ++ks)
      #pragma unroll
      for (int mi = 0; mi < 4; ++mi) {
        acc[mi] = __builtin_amdgcn_mfma_f32_16x16x32_f16(ahi[mi][ks], b[ks], acc[mi], 0, 0, 0);
        acc[mi] = __builtin_amdgcn_mfma_f32_16x16x32_f16(alo[mi][ks], b[ks], acc[mi], 0, 0, 0);
      }
    #pragma unroll
    for (int mi = 0; mi < 4; ++mi)
      #pragma unroll
      for (int q = 0; q < 4; ++q) {
        const int rowl = mi * 16 + lgrp * 4 + q;
        const bool kept = (mk[rowl][i] >> cbit) & 1ull;
        const float e = acc[mi][q];
        lreg[mi][q] += (kept && e > 0.f) ? __expf(e - CSHIFT) : 0.f;
      }
  };
  f16x8 bA[2], bB[2];
  loadB(bA, 0); loadB(bB, 1);
  for (int i = 0; i < ntw; i += 2) {
    f16x8 nA[2], nB[2];
    loadB(nA, i + 2);
    loadB(nB, i + 3);
    compute(i, bA);
    compute(i + 1, bB);
    bA[0] = nA[0]; bA[1] = nA[1];
    bB[0] = nB[0]; bB[1] = nB[1];
  }
  #pragma unroll
  for (int mi = 0; mi < 4; ++mi)
    #pragma unroll
    for (int q = 0; q < 4; ++q) {
      float l0 = lreg[mi][q];
      #pragma unroll
      for (int s = 1; s < 16; s <<= 1) l0 += __shfl_xor(l0, s, 64);
      lreg[mi][q] = l0;
    }
  if (lrow == 0) {
    #pragma unroll
    for (int mi = 0; mi < 4; ++mi)
      #pragma unroll
      for (int q = 0; q < 4; ++q) {
        const int rl = mi * 16 + lgrp * 4 + q;
        red_l[wave][rl] = lreg[mi][q];
      }
  }
  __syncthreads();
  if (threadIdx.x < 64) {
    const int rl = threadIdx.x;
    const float l0 = red_l[0][rl] + red_l[1][rl] + red_l[2][rl] + red_l[3][rl];
    const size_t o = ((size_t)chunk * NHEAD + h) * NPAD + r0 + rl;
    lpart[o] = l0;
  }
}

// ---------------- merge partial l over the 8 column chunks ----------------
__global__ void k_merge(const float* __restrict__ lpart, float* __restrict__ lfin) {
  const int i = blockIdx.x * 256 + threadIdx.x;
  if (i >= NHEAD * NPAD) return;
  float l0 = 0.f;
  #pragma unroll
  for (int c = 0; c < 8; ++c) l0 += lpart[(size_t)c * (NHEAD * NPAD) + i];
  lfin[i] = l0;
}

// ---------------- pass2: A[m][n] = sum_h attn_h[m][n]  (bf16), R18 shape + single-exp epilogue ----------------
__global__ __launch_bounds__(256) void k_pass2(const u16* __restrict__ g2hi, const u16* __restrict__ g2lo,
                                               const u16* __restrict__ h1f16,
                                               const u64* __restrict__ maskbits,
                                               const float* __restrict__ lfin,
                                               u16* __restrict__ Amat) {
  const int r0 = blockIdx.x * 32;
  const int chunk = blockIdx.y;          // 0..23, 256 cols each (last: 128)
  const int c0 = chunk * 256;
  const int nt = (chunk < 23) ? 16 : 8;
  const int wave = threadIdx.x >> 6, lane = threadIdx.x & 63;
  const int lrow = lane & 15, lgrp = lane >> 4;
  const u32 cbit = (u32)(wave * 16 + lrow);
  __shared__ float sv[NHEAD][32], suS[32];
  __shared__ u64 mk[32][4];
  if (threadIdx.x < NHEAD * 32) {
    const int h = threadIdx.x >> 5, rl = threadIdx.x & 31;
    const float lv = lfin[(size_t)h * NPAD + r0 + rl];
    sv[h][rl] = (lv > 0.f) ? (1.f / lv) : 0.f;
  }
  if (threadIdx.x >= 128 && threadIdx.x < 160) {
    const int rl = threadIdx.x - 128;
    float s = 0.f;
    #pragma unroll
    for (int h = 0; h < NHEAD; ++h) {
      const float lv = lfin[(size_t)h * NPAD + r0 + rl];
      s += (lv > 0.f) ? 0.f : (1.f / 6000.f);  // empty row: uniform fallback
    }
    suS[rl] = s;
  }
  {
    const int wb = chunk * 4;
    for (int i = threadIdx.x; i < 32 * 4; i += 256) {
      const int r = i >> 2, wi = i & 3;
      mk[r][wi] = (wb + wi < MWORDS) ? maskbits[(size_t)(r0 + r) * MWORDS + wb + wi] : 0ull;
    }
  }
  __syncthreads();
  const int ntw = nt >> 2;
  f32x4 wsum[4][2] = {};
  #pragma unroll
  for (int h = 0; h < NHEAD; ++h) {
    f16x8 ahi[2][2], alo[2][2];
    #pragma unroll
    for (int mi = 0; mi < 2; ++mi)
      #pragma unroll
      for (int ks = 0; ks < 2; ++ks) {
        const size_t off = ((size_t)h * NPAD + (r0 + mi * 16 + lrow)) * DDIM + ks * 32 + lgrp * 8;
        ahi[mi][ks] = *(const f16x8*)(g2hi + off);
        alo[mi][ks] = *(const f16x8*)(g2lo + off);
      }
    const u16* hb = h1f16 + (size_t)h * NPAD * DDIM + lrow * DDIM + lgrp * 8;
    auto loadB = [&](f16x8* dst, int i) {
      const int ii = (i < ntw) ? i : (ntw - 1);
      const size_t off = (size_t)(c0 + (wave + 4 * ii) * 16) * DDIM;
      dst[0] = *(const f16x8*)(hb + off);
      dst[1] = *(const f16x8*)(hb + off + 32);
    };
    auto compute = [&](int i, const f16x8* b) {
      if (i >= ntw) return;
      f32x4 acc[2] = {};
      #pragma unroll
      for (int ks = 0; ks < 2; ++ks)
        #pragma unroll
        for (int mi = 0; mi < 2; ++mi) {
          acc[mi] = __builtin_amdgcn_mfma_f32_16x16x32_f16(ahi[mi][ks], b[ks], acc[mi], 0, 0, 0);
          acc[mi] = __builtin_amdgcn_mfma_f32_16x16x32_f16(alo[mi][ks], b[ks], acc[mi], 0, 0, 0);
        }
      #pragma unroll
      for (int mi = 0; mi < 2; ++mi)
        #pragma unroll
        for (int q = 0; q < 4; ++q) {
          const int rl = mi * 16 + lgrp * 4 + q;
          const bool kept = (mk[rl][i] >> cbit) & 1ull;
          const float v = acc[mi][q];
          wsum[i][mi][q] += (kept && v > 0.f) ? (__expf(v - CSHIFT) * sv[h][rl]) : 0.f;
        }
    };
    f16x8 b0[2], b1[2], b2[2], b3[2];
    loadB(b0, 0); loadB(b1, 1); loadB(b2, 2); loadB(b3, 3);
    compute(0, b0);
    compute(1, b1);
    compute(2, b2);
    compute(3, b3);
  }
  // write phase: add uniform fallback once, store bf16
  #pragma unroll
  for (int ti = 0; ti < 4; ++ti) {
    if (ti < ntw) {
      const int col = c0 + (wave + 4 * ti) * 16 + lrow;
      const float suAdd = (col < N_NODES) ? 1.f : 0.f;
      #pragma unroll
      for (int mi = 0; mi < 2; ++mi)
        #pragma unroll
        for (int q = 0; q < 4; ++q) {
          const int rl = mi * 16 + lgrp * 4 + q;
          const int row = r0 + rl;
          const float wv = wsum[ti][mi][q] + suAdd * suS[rl];
          Amat[(size_t)row * NPAD + col] = f2bf(wv);
        }
    }
  }
}

// ---------------- out0 = (A @ tf) / 4   (M=NPAD, N=256, K=NPAD) -> f32 ----------------
__global__ __launch_bounds__(256) void k_gemm_pv(const u16* __restrict__ Amat,
                                                 const u16* __restrict__ tfT,   // [256][NPAD]
                                                 float* __restrict__ out0) {
  const int r0 = blockIdx.x * 32;
  const int wave = threadIdx.x >> 6, lane = threadIdx.x & 63;
  const int lrow = lane & 15, lgrp = lane >> 4;
  const int n0 = wave * 64;
  f32x4 acc[2][4] = {};
  for (int ks = 0; ks < NPAD; ks += 32) {
    const int kb = ks + lgrp * 8;
    bf16x8 a[2], b[4];
    #pragma unroll
    for (int mi = 0; mi < 2; ++mi)
      a[mi] = *(const bf16x8*)(Amat + (size_t)(r0 + mi * 16 + lrow) * NPAD + kb);
    #pragma unroll
    for (int ni = 0; ni < 4; ++ni)
      b[ni] = *(const bf16x8*)(tfT + (size_t)(n0 + ni * 16 + lrow) * NPAD + kb);
    #pragma unroll
    for (int mi = 0; mi < 2; ++mi)
      #pragma unroll
      for (int ni = 0; ni < 4; ++ni)
        acc[mi][ni] = __builtin_amdgcn_mfma_f32_16x16x32_bf16(a[mi], b[ni], acc[mi][ni], 0, 0, 0);
  }
  #pragma unroll
  for (int mi = 0; mi < 2; ++mi)
    #pragma unroll
    for (int ni = 0; ni < 4; ++ni) {
      const int col = n0 + ni * 16 + lrow;
      const int rbase = r0 + mi * 16 + lgrp * 4;
      #pragma unroll
      for (int q = 0; q < 4; ++q) {
        const int row = rbase + q;
        if (row < N_NODES) out0[(size_t)row * TDIM + col] = acc[mi][ni][q] * 0.25f;
      }
    }
}

// ---------------- launcher ----------------
extern "C" void kernel_launch(void* const* d_in, const int* in_sizes, int n_in,
                              void* d_out, int out_size, void* d_ws, size_t ws_size,
                              hipStream_t stream) {
  (void)in_sizes; (void)n_in; (void)out_size; (void)ws_size;
  const int*   bias  = (const int*)  d_in[0];
  const float* emb_d = (const float*)d_in[1];
  const float* emb_s = (const float*)d_in[2];
  const float* fs    = (const float*)d_in[3];
  const float* W     = (const float*)d_in[4];
  const float* W2    = (const float*)d_in[5];
  const float* fcw   = (const float*)d_in[6];
  const float* fcb   = (const float*)d_in[7];
  const float* decw  = (const float*)d_in[8];
  const float* decb  = (const float*)d_in[9];
  float* out0 = (float*)d_out;
  float* out1 = out0 + (size_t)N_NODES * TDIM;   // f32 outputs, concatenated

  char* base = (char*)d_ws;
  size_t off = 0;
  auto alloc = [&](size_t bytes) -> void* {
    off = (off + 255) & ~(size_t)255;
    void* p = base + off;
    off += bytes;
    return p;
  };
  u16*   Amat   = (u16*)  alloc((size_t)NPAD * NPAD * 2);          // 72.4 MB
  u16*   tf_b   = (u16*)  alloc((size_t)NPAD * TDIM * 2);
  u16*   tfT_b  = (u16*)  alloc((size_t)TDIM * NPAD * 2);
  u16*   fs_b   = (u16*)  alloc((size_t)NPAD * FDIM * 2);
  u16*   fcw_b  = (u16*)  alloc((size_t)TDIM * FDIM * 2);
  u16*   decw_b = (u16*)  alloc((size_t)FDIM * TDIM * 2);
  u16*   h1f16  = (u16*)  alloc((size_t)NHEAD * NPAD * DDIM * 2);
  u16*   g2hi   = (u16*)  alloc((size_t)NHEAD * NPAD * DDIM * 2);
  u16*   g2lo   = (u16*)  alloc((size_t)NHEAD * NPAD * DDIM * 2);
  u64*   maskb  = (u64*)  alloc((size_t)NPAD * MWORDS * 8);
  float* lpart  = (float*)alloc((size_t)8 * NHEAD * NPAD * 4);
  float* lfin   = (float*)alloc((size_t)NHEAD * NPAD * 4);
  u32*   cls    = (u32*)  alloc((size_t)NPAD * 4);

  hipLaunchKernelGGL(k_prep,    dim3((NPAD * FDIM) / 256), dim3(256), 0, stream,
                     fs, fcw, decw, fs_b, fcw_b, decw_b, cls);
  hipLaunchKernelGGL(k_hgen,    dim3(NPAD),                dim3(256), 0, stream,
                     emb_s, emb_d, W, W2, h1f16, g2hi, g2lo);
  hipLaunchKernelGGL(k_gemm_tf, dim3(NPAD / 32),           dim3(256), 0, stream,
                     fs_b, fcw_b, fcb, tf_b, tfT_b);
  hipLaunchKernelGGL(k_gemm_fh, dim3(NPAD / 32),           dim3(256), 0, stream,
                     tf_b, decw_b, decb, out1);
  hipLaunchKernelGGL(k_mask,    dim3(NPAD),                dim3(256), 0, stream,
                     bias, cls, maskb);
  hipLaunchKernelGGL(k_pass1,   dim3(NPAD / 64, 8, NHEAD), dim3(256), 0, stream,
                     g2hi, g2lo, h1f16, maskb, lpart);
  hipLaunchKernelGGL(k_merge,   dim3((NHEAD * NPAD) / 256),dim3(256), 0, stream,
                     lpart, lfin);
  hipLaunchKernelGGL(k_pass2,   dim3(NPAD / 32, 24),       dim3(256), 0, stream,
                     g2hi, g2lo, h1f16, maskb, lfin, Amat);
  hipLaunchKernelGGL(k_gemm_pv, dim3(NPAD / 32),           dim3(256), 0, stream,
                     Amat, tfT_b, out0);
}